// Round 5
// baseline (229.893 us; speedup 1.0000x reference)
//
#include <hip/hip_runtime.h>

// Problem constants (match reference file)
constexpr int B = 32;
constexpr int L = 512;
constexpr int D = 384;
constexpr int T = 4096;
constexpr int VPR  = D / 4;                // float4 per output row = 96
constexpr int OUT0 = B * T * D;            // elements in first output
constexpr int BS   = 256;                  // threads per block
constexpr int RPB  = 32;                   // output rows per block
constexpr int BPB  = T / RPB;              // 128 blocks per batch
constexpr int NBLK = B * BPB;              // 4096 blocks
constexpr int PASSES = RPB * VPR / BS;     // 12 float4 per thread
constexpr int NWAVE  = BS / 64;            // 4 waves per block

typedef float v4f __attribute__((ext_vector_type(4)));  // native vec for NT ops

// Single fused kernel:
//  - per-block redundant scan of dur[b][:] (shfl wave-scan + wave-sum fixup)
//  - mask staged in LDS
//  - 32 binary searches in LDS (10 fixed iterations: 512 candidates need
//    ceil steps to 0 undecided = 10; converged-early iterations are no-ops
//    because s_cum[lo] > j at the answer)
//  - contiguous 48 KB nontemporal output stream per block
//  - chunk==0 blocks also write exp_dur (as f32)
__global__ __launch_bounds__(BS) void fused_k(const v4f* __restrict__ seq,
                                              const int* __restrict__ dur,
                                              const int* __restrict__ mask,
                                              v4f*       __restrict__ out,
                                              float*     __restrict__ expd) {
    __shared__ int s_cum[L];
    __shared__ int s_mask[L];
    __shared__ int s_wsum[NWAVE];
    __shared__ int s_src[RPB];

    const int blk   = blockIdx.x;
    const int b     = blk >> 7;            // / BPB (128)
    const int chunk = blk & (BPB - 1);
    const int row0  = chunk * RPB;         // first output slot j of this block
    const int tid   = threadIdx.x;
    const int lane  = tid & 63;
    const int wave  = tid >> 6;

    // --- load dur + mask (2 elements per thread, coalesced int2) ---
    const int2 d2 = ((const int2*)(dur  + b * L))[tid];
    const int2 m2 = ((const int2*)(mask + b * L))[tid];
    const int e0 = d2.x, e1 = d2.y;

    // --- inclusive scan of per-thread pair sums: wave shfl scan ---
    int v = e0 + e1;
    #pragma unroll
    for (int off = 1; off < 64; off <<= 1) {
        int u = __shfl_up(v, off, 64);
        if (lane >= off) v += u;
    }
    if (lane == 63) s_wsum[wave] = v;
    s_mask[2 * tid]     = m2.x;
    s_mask[2 * tid + 1] = m2.y;
    __syncthreads();

    int woff = 0;
    #pragma unroll
    for (int w = 0; w < NWAVE; ++w)
        if (w < wave) woff += s_wsum[w];
    const int excl = v + woff - (e0 + e1); // exclusive prefix before e0
    s_cum[2 * tid]     = excl + e0;
    s_cum[2 * tid + 1] = excl + e0 + e1;
    __syncthreads();

    // --- 32 binary searches in LDS (threads 0..RPB-1) ---
    if (tid < RPB) {
        const int j = row0 + tid;
        const int total = s_cum[L - 1];
        int res = -1;
        if (j < total) {
            int lo = 0, hi = L;            // j < total => answer <= L-1
            #pragma unroll
            for (int it = 0; it < 10; ++it) {  // 10 = full convergence for 512
                int mid = (lo + hi) >> 1;
                if (s_cum[mid] <= j) lo = mid + 1; else hi = mid;
            }
            res = s_mask[lo] ? -1 : (b * L + lo);
        }
        s_src[tid] = res;
    }
    __syncthreads();

    // --- copy loop: RPB*VPR = 3072 float4, contiguous 48 KB per block ---
    v4f* obase = out + (size_t)(b * T + row0) * VPR;
    #pragma unroll
    for (int p = 0; p < PASSES; ++p) {
        const int idx = p * BS + tid;      // 0..3071
        const int r   = idx / VPR;         // constant div -> magic mul
        const int col = idx - r * VPR;
        const int s   = s_src[r];
        v4f vv = (v4f)(0.f);
        if (s >= 0) vv = seq[s * VPR + col];
        __builtin_nontemporal_store(vv, &obase[idx]);
    }

    // --- exp_dur output (one block per batch does it) ---
    if (chunk == 0) {
        expd[b * L + 2 * tid]     = (float)e0;
        expd[b * L + 2 * tid + 1] = (float)e1;
    }
}

extern "C" void kernel_launch(void* const* d_in, const int* in_sizes, int n_in,
                              void* d_out, int out_size, void* d_ws, size_t ws_size,
                              hipStream_t stream) {
    const float* seq  = (const float*)d_in[0];
    const int*   dur  = (const int*)d_in[1];
    const int*   mask = (const int*)d_in[2];
    // d_in[3] = max_length scalar (4096 == T)

    float* out      = (float*)d_out;
    float* expd_out = out + OUT0;

    fused_k<<<NBLK, BS, 0, stream>>>((const v4f*)seq, dur, mask,
                                     (v4f*)out, expd_out);
}